// Round 11
// baseline (1205.772 us; speedup 1.0000x reference)
//
#include <hip/hip_runtime.h>
#include <hip/hip_bf16.h>

#define N_USERS 100000
#define N_ITEMS 50000
#define N_TOT   150000
#define D       64
#define NBUCK   ((N_ITEMS + 255) >> 8)   // 196 coarse buckets of 256 items
#define BCAP    12288                    // bucket capacity (mean ~10.2K, +18 sigma)
#define CONVU_B 391                      // ceil(100000/256): user conv+ptr blocks
#define FLAG_B  48                       // ceil(3*4096/256)
#define SCAT_K  32                       // edges per thread in scatter section
#define U_UNITS 25000                    // 100000 user rows / 4 per block
#define I_UNITS 12500                    // 50000 item rows / 4 per block

typedef float v2f __attribute__((ext_vector_type(2)));

// ---------------- helpers ----------------
__device__ __forceinline__ unsigned bf16rn(float f) {        // fp32 -> bf16 bits (RNE)
    unsigned x = __float_as_uint(f);
    return (x + 0x7FFFu + ((x >> 16) & 1u)) >> 16;
}
__device__ __forceinline__ unsigned packbf(float a, float b) {
    return bf16rn(a) | (bf16rn(b) << 16);
}
__device__ __forceinline__ int lower_bound(const int* __restrict__ a, int n, int key) {
    int lo = 0, hi = n;
    while (lo < hi) {
        int mid = (lo + hi) >> 1;
        if (a[mid] < key) lo = mid + 1; else hi = mid;
    }
    return lo;
}

// ---------------- preprocessing kernel A ----------------
__global__ __launch_bounds__(256) void preA_kernel(
        const float* __restrict__ embeds, const int* __restrict__ rows,
        const int* __restrict__ cols, int* __restrict__ user_ptr,
        unsigned* __restrict__ ebfS, float* __restrict__ invrow,
        const int* __restrict__ users, const int* __restrict__ pos,
        const int* __restrict__ neg, unsigned char* __restrict__ flags,
        int* __restrict__ ccur, int* __restrict__ tmp,
        unsigned short* __restrict__ cols16, int E, int B) {
    int b = blockIdx.x, t = threadIdx.x;
    if (b < CONVU_B) {
        __shared__ int ptr_s[257];
        __shared__ float inv_s[256];
        int base = b * 256;
        int r = base + t;
        int v = lower_bound(rows, E, r);
        ptr_s[t] = v;
        if (r <= N_USERS) user_ptr[r] = v;
        if (t == 0) ptr_s[256] = lower_bound(rows, E, base + 256);
        __syncthreads();
        if (r < N_USERS) {
            int deg = ptr_s[t + 1] - ptr_s[t];
            float inv = (deg > 0) ? (float)(1.0 / sqrt((double)deg)) : 0.f;
            inv_s[t] = inv;
            invrow[r] = inv;
        } else inv_s[t] = 0.f;
        __syncthreads();
        int fl = t & 15;
        #pragma unroll
        for (int i = 0; i < 16; ++i) {
            int lr = i * 16 + (t >> 4);
            int row = base + lr;
            if (row < N_USERS) {
                float inv = inv_s[lr];
                float4 v4 = *(const float4*)(embeds + (size_t)row * D + fl * 4);
                uint2 o;
                o.x = packbf(inv * v4.x, inv * v4.y);
                o.y = packbf(inv * v4.z, inv * v4.w);
                *(uint2*)(ebfS + (size_t)row * 32 + fl * 2) = o;
            }
        }
    } else if (b < CONVU_B + FLAG_B) {
        int k = (b - CONVU_B) * 256 + t;
        if (k < 3 * B) {
            int row;
            if (k < B)          row = users[k];
            else if (k < 2 * B) row = N_USERS + pos[k - B];
            else                row = N_USERS + neg[k - 2 * B];
            flags[row] = 1;
        }
    } else {
        __shared__ int ebuf[256 * SCAT_K];            // 32 KB payloads
        __shared__ unsigned char bbuf[256 * SCAT_K];  // 8 KB bucket ids
        __shared__ int cnt[NBUCK];
        __shared__ int basep[NBUCK];
        int chunk = (b - CONVU_B - FLAG_B) * (256 * SCAT_K);
        if (t < NBUCK) cnt[t] = 0;
        __syncthreads();
        #pragma unroll 4
        for (int k = 0; k < SCAT_K; ++k) {
            int e = chunk + k * 256 + t;
            int idx = k * 256 + t;
            if (e < E) {
                int i = cols[e] - N_USERS;
                cols16[e] = (unsigned short)i;
                int bu = i >> 8;
                ebuf[idx] = ((i & 255) << 17) | rows[e];
                bbuf[idx] = (unsigned char)bu;
                atomicAdd(&cnt[bu], 1);
            } else bbuf[idx] = 255;                    // invalid (>195)
        }
        __syncthreads();
        if (t < NBUCK) {
            int c = cnt[t];
            basep[t] = c ? atomicAdd(&ccur[t], c) : 0;
            cnt[t] = 0;
        }
        __syncthreads();
        #pragma unroll 4
        for (int k = 0; k < SCAT_K; ++k) {
            int idx = k * 256 + t;
            int bu = bbuf[idx];
            if (bu < NBUCK) {
                int pos2 = basep[bu] + atomicAdd(&cnt[bu], 1);
                if (pos2 < BCAP)
                    tmp[(size_t)bu * BCAP + pos2] = ebuf[idx];
            }
        }
    }
}

// ---------------- preprocessing kernel B ----------------
__global__ __launch_bounds__(256) void preB_kernel(
        const int* __restrict__ tmp, const int* __restrict__ ccur,
        const float* __restrict__ embeds,
        int* __restrict__ item_beg, int* __restrict__ item_end,
        int* __restrict__ nbr, unsigned* __restrict__ ebfS,
        unsigned* __restrict__ bb1, float* __restrict__ invrow) {
    int b = blockIdx.x, t = threadIdx.x;
    if (b == NBUCK) {
        if (t < 16) {
            *(uint2*)(ebfS + (size_t)N_TOT * 32 + t * 2) = make_uint2(0u, 0u);
            *(uint2*)(bb1  + (size_t)N_TOT * 32 + t * 2) = make_uint2(0u, 0u);
        }
        if (t == 0) invrow[N_TOT] = 0.f;
        return;
    }
    __shared__ int stage[BCAP];    // 48 KB
    __shared__ int hist[256];
    __shared__ int scn[256];
    __shared__ int curs[256];
    __shared__ float inv_s[256];
    int n = ccur[b]; if (n > BCAP) n = BCAP;
    const int* src = tmp + (size_t)b * BCAP;
    hist[t] = 0;
    __syncthreads();
    for (int p = t; p < n; p += 256) {
        int q = src[p];
        stage[p] = q;
        atomicAdd(&hist[q >> 17], 1);
    }
    __syncthreads();
    scn[t] = hist[t];
    __syncthreads();
    for (int off = 1; off < 256; off <<= 1) {
        int x = (t >= off) ? scn[t - off] : 0;
        __syncthreads();
        scn[t] += x;
        __syncthreads();
    }
    {
        int excl = scn[t] - hist[t];
        curs[t] = excl;
        int gi = (b << 8) + t;
        float inv = (hist[t] > 0) ? (float)(1.0 / sqrt((double)hist[t])) : 0.f;
        inv_s[t] = inv;
        if (gi < N_ITEMS) {
            item_beg[gi] = b * BCAP + excl;
            item_end[gi] = b * BCAP + excl + hist[t];
            invrow[N_USERS + gi] = inv;
        }
    }
    __syncthreads();
    int* dst = nbr + (size_t)b * BCAP;
    for (int p = t; p < n; p += 256) {
        int q = stage[p];
        int pos = atomicAdd(&curs[q >> 17], 1);
        dst[pos] = q & 0x1FFFF;
    }
    int fl = t & 15;
    #pragma unroll
    for (int i = 0; i < 16; ++i) {
        int lr = i * 16 + (t >> 4);
        int gi = (b << 8) + lr;
        if (gi < N_ITEMS) {
            int row = N_USERS + gi;
            float inv = inv_s[lr];
            float4 v4 = *(const float4*)(embeds + (size_t)row * D + fl * 4);
            uint2 o;
            o.x = packbf(inv * v4.x, inv * v4.y);
            o.y = packbf(inv * v4.z, inv * v4.w);
            *(uint2*)(ebfS + (size_t)row * 32 + fl * 2) = o;
        }
    }
}

// ---------------- propagation (layers 1,2: all rows) ----------------
// XCD-specialized via ground-truth XCC_ID + dynamic work queues:
// XCDs 0-3 pop user-row units (gather 6.4 MB item table), XCDs 4-7 pop
// item-row units (gather 12.8 MB user table); steal-on-overflow guarantees
// every unit is processed exactly once for any block->XCD distribution.
__global__ __launch_bounds__(256) void agg_kernel(
        const unsigned* __restrict__ gsrc,   // scaled bf16 rows, 32 uints/row
        float* __restrict__ nxt, unsigned* __restrict__ nxtb,
        const float* __restrict__ invrow,
        const unsigned char* __restrict__ flags,
        const int* __restrict__ user_ptr, const unsigned short* __restrict__ cols16,
        const int* __restrict__ item_beg, const int* __restrict__ item_end,
        const int* __restrict__ nbr, int* __restrict__ ctr) {
    __shared__ int unit_s;
    if (threadIdx.x == 0) {
        int xcc;
        asm volatile("s_getreg_b32 %0, hwreg(HW_REG_XCC_ID)" : "=s"(xcc));
        int side = (xcc >> 2) & 1;           // 0: XCD0-3 -> users, 1: XCD4-7 -> items
        int unit;
        if (side == 0) {
            int idx = atomicAdd(&ctr[0], 1);
            unit = (idx < U_UNITS) ? idx : (U_UNITS + atomicAdd(&ctr[1], 1));
        } else {
            int idx = atomicAdd(&ctr[1], 1);
            unit = (idx < I_UNITS) ? (U_UNITS + idx) : atomicAdd(&ctr[0], 1);
        }
        unit_s = unit;
    }
    __syncthreads();
    int unit = unit_s;
    int lw   = (int)(threadIdx.x >> 6);
    int lane = (int)(threadIdx.x & 63);
    int g  = lane >> 3;
    int fl = lane & 7;

    bool is_user = unit < U_UNITS;
    int wave, s, epos, dummy;
    const unsigned* sb;
    if (is_user) {
        wave = unit * 4 + lw;
        s = user_ptr[wave]; epos = user_ptr[wave + 1];
        sb = gsrc + (size_t)N_USERS * 32; dummy = N_ITEMS;
    } else {
        int i = (unit - U_UNITS) * 4 + lw;
        wave = N_USERS + i;
        s = item_beg[i]; epos = item_end[i];
        sb = gsrc; dummy = N_TOT;
    }

    v2f a0 = {0.f, 0.f}, a1 = {0.f, 0.f}, a2 = {0.f, 0.f}, a3 = {0.f, 0.f};

    for (int base = s; base < epos; base += 64) {
        int cnt = epos - base; if (cnt > 64) cnt = 64;
        int col = dummy;
        if (lane < cnt)
            col = is_user ? (int)cols16[base + lane] : nbr[base + lane];
        int tcount = (cnt + 7) >> 3;
        #pragma unroll 4
        for (int t = 0; t < tcount; ++t) {
            int c = __shfl(col, 8 * t + g);
            uint4 q = *(const uint4*)(sb + (size_t)c * 32 + fl * 4);
            v2f p0 = {__uint_as_float(q.x << 16), __uint_as_float(q.x & 0xFFFF0000u)};
            v2f p1 = {__uint_as_float(q.y << 16), __uint_as_float(q.y & 0xFFFF0000u)};
            v2f p2 = {__uint_as_float(q.z << 16), __uint_as_float(q.z & 0xFFFF0000u)};
            v2f p3 = {__uint_as_float(q.w << 16), __uint_as_float(q.w & 0xFFFF0000u)};
            a0 += p0; a1 += p1; a2 += p2; a3 += p3;
        }
    }
    float acc[8] = {a0.x, a0.y, a1.x, a1.y, a2.x, a2.y, a3.x, a3.y};
    #pragma unroll
    for (int j = 0; j < 8; ++j) {
        acc[j] += __shfl_xor(acc[j], 8);
        acc[j] += __shfl_xor(acc[j], 16);
        acc[j] += __shfl_xor(acc[j], 32);
    }
    if (lane < 8) {
        float inv = invrow[wave];
        float f[8];
        #pragma unroll
        for (int j = 0; j < 8; ++j) f[j] = inv * acc[j];
        uint4 o;
        o.x = packbf(inv * f[0], inv * f[1]); o.y = packbf(inv * f[2], inv * f[3]);
        o.z = packbf(inv * f[4], inv * f[5]); o.w = packbf(inv * f[6], inv * f[7]);
        *(uint4*)(nxtb + (size_t)wave * 32 + fl * 4) = o;
        if (flags[wave]) {
            size_t ro = (size_t)wave * D + fl * 8;
            *(float4*)(nxt + ro)     = make_float4(f[0], f[1], f[2], f[3]);
            *(float4*)(nxt + ro + 4) = make_float4(f[4], f[5], f[6], f[7]);
        }
    }
}

// ---------------- layer 3 fused with epilogue: only output slots ----------------
__global__ __launch_bounds__(256) void agg3_fused_kernel(
        const unsigned* __restrict__ gsrc,
        const float* __restrict__ e0, const float* __restrict__ e1,
        const float* __restrict__ e2, const float* __restrict__ invrow,
        const int* __restrict__ users, const int* __restrict__ pos,
        const int* __restrict__ neg,
        const int* __restrict__ user_ptr, const unsigned short* __restrict__ cols16,
        const int* __restrict__ item_beg, const int* __restrict__ item_end,
        const int* __restrict__ nbr,
        float* __restrict__ out, int B) {
    int slot = (int)((blockIdx.x * blockDim.x + threadIdx.x) >> 6);
    int lane = (int)(threadIdx.x & 63);
    if (slot >= 3 * B) return;
    int g  = lane >> 3;
    int fl = lane & 7;

    int row;
    if (slot < B)          row = users[slot];
    else if (slot < 2 * B) row = N_USERS + pos[slot - B];
    else                   row = N_USERS + neg[slot - 2 * B];

    bool is_user = row < N_USERS;
    int s, epos, dummy;
    const unsigned* sb;
    if (is_user) {
        s = user_ptr[row]; epos = user_ptr[row + 1];
        sb = gsrc + (size_t)N_USERS * 32; dummy = N_ITEMS;
    } else {
        int i = row - N_USERS; s = item_beg[i]; epos = item_end[i];
        sb = gsrc; dummy = N_TOT;
    }

    v2f a0 = {0.f, 0.f}, a1 = {0.f, 0.f}, a2 = {0.f, 0.f}, a3 = {0.f, 0.f};

    for (int base = s; base < epos; base += 64) {
        int cnt = epos - base; if (cnt > 64) cnt = 64;
        int col = dummy;
        if (lane < cnt)
            col = is_user ? (int)cols16[base + lane] : nbr[base + lane];
        int tcount = (cnt + 7) >> 3;
        #pragma unroll 4
        for (int t = 0; t < tcount; ++t) {
            int c = __shfl(col, 8 * t + g);
            uint4 q = *(const uint4*)(sb + (size_t)c * 32 + fl * 4);
            v2f p0 = {__uint_as_float(q.x << 16), __uint_as_float(q.x & 0xFFFF0000u)};
            v2f p1 = {__uint_as_float(q.y << 16), __uint_as_float(q.y & 0xFFFF0000u)};
            v2f p2 = {__uint_as_float(q.z << 16), __uint_as_float(q.z & 0xFFFF0000u)};
            v2f p3 = {__uint_as_float(q.w << 16), __uint_as_float(q.w & 0xFFFF0000u)};
            a0 += p0; a1 += p1; a2 += p2; a3 += p3;
        }
    }
    float acc[8] = {a0.x, a0.y, a1.x, a1.y, a2.x, a2.y, a3.x, a3.y};
    #pragma unroll
    for (int j = 0; j < 8; ++j) {
        acc[j] += __shfl_xor(acc[j], 8);
        acc[j] += __shfl_xor(acc[j], 16);
        acc[j] += __shfl_xor(acc[j], 32);
    }
    if (lane < 8) {
        float inv = invrow[row];
        size_t ro = (size_t)row * D + fl * 8;
        float4 x0 = *(const float4*)(e0 + ro), x1 = *(const float4*)(e0 + ro + 4);
        float4 y0 = *(const float4*)(e1 + ro), y1 = *(const float4*)(e1 + ro + 4);
        float4 z0 = *(const float4*)(e2 + ro), z1 = *(const float4*)(e2 + ro + 4);
        float4 r0, r1;
        r0.x = (x0.x + y0.x + z0.x + inv * acc[0]) * 0.25f;
        r0.y = (x0.y + y0.y + z0.y + inv * acc[1]) * 0.25f;
        r0.z = (x0.z + y0.z + z0.z + inv * acc[2]) * 0.25f;
        r0.w = (x0.w + y0.w + z0.w + inv * acc[3]) * 0.25f;
        r1.x = (x1.x + y1.x + z1.x + inv * acc[4]) * 0.25f;
        r1.y = (x1.y + y1.y + z1.y + inv * acc[5]) * 0.25f;
        r1.z = (x1.z + y1.z + z1.z + inv * acc[6]) * 0.25f;
        r1.w = (x1.w + y1.w + z1.w + inv * acc[7]) * 0.25f;
        size_t oo = (size_t)slot * D + fl * 8;
        *(float4*)(out + oo)     = r0;
        *(float4*)(out + oo + 4) = r1;
    }
}

extern "C" void kernel_launch(void* const* d_in, const int* in_sizes, int n_in,
                              void* d_out, int out_size, void* d_ws, size_t ws_size,
                              hipStream_t stream) {
    const float* embeds = (const float*)d_in[0];
    const int*   rows   = (const int*)d_in[2];
    const int*   cols   = (const int*)d_in[3];
    const int*   users  = (const int*)d_in[4];
    const int*   pos    = (const int*)d_in[5];
    const int*   neg    = (const int*)d_in[6];
    const int E2 = in_sizes[1];
    const int E  = E2 / 2;
    const int B  = in_sizes[4];

    char* ws = (char*)d_ws;
    size_t off = 0;
    auto alloc = [&](size_t bytes) { void* p = ws + off; off = (off + bytes + 255) & ~(size_t)255; return p; };
    float*    buf1     = (float*)   alloc((size_t)N_TOT * D * sizeof(float));     // flagged fp32 L1
    float*    buf2     = (float*)   alloc((size_t)N_TOT * D * sizeof(float));     // flagged fp32 L2
    unsigned* ebfS     = (unsigned*)alloc((size_t)(N_TOT + 1) * 32 * sizeof(unsigned)); // scaled bf16 (+zero row); reused as bb2
    unsigned* bb1      = (unsigned*)alloc((size_t)(N_TOT + 1) * 32 * sizeof(unsigned));
    int*      nbr      = (int*)     alloc((size_t)NBUCK * BCAP * sizeof(int));    // padded item CSR (user idx)
    unsigned short* cols16 = (unsigned short*)alloc((size_t)E * sizeof(unsigned short));
    int*      user_ptr = (int*)     alloc((size_t)(N_USERS + 1) * sizeof(int));
    int*      ccur     = (int*)     alloc((size_t)NBUCK * sizeof(int));
    int*      item_beg = (int*)     alloc((size_t)N_ITEMS * sizeof(int));
    int*      item_end = (int*)     alloc((size_t)N_ITEMS * sizeof(int));
    float*    invrow   = (float*)   alloc((size_t)(N_TOT + 1) * sizeof(float));
    unsigned char* flags = (unsigned char*)alloc((size_t)N_TOT);
    int*      ctrs     = (int*)     alloc((size_t)4 * sizeof(int));   // work queues (2 per agg dispatch)
    int*      tmp      = (int*)buf1;   // alias: buf1 written only after preB

    // --- preprocessing (2 fused kernels) ---
    hipMemsetAsync(ccur, 0, (size_t)NBUCK * sizeof(int), stream);
    hipMemsetAsync(flags, 0, (size_t)N_TOT, stream);
    hipMemsetAsync(ctrs, 0, 4 * sizeof(int), stream);
    const int scatB = (E + 256 * SCAT_K - 1) / (256 * SCAT_K);
    preA_kernel<<<CONVU_B + FLAG_B + scatB, 256, 0, stream>>>(
        embeds, rows, cols, user_ptr, ebfS, invrow, users, pos, neg, flags,
        ccur, tmp, cols16, E, B);
    preB_kernel<<<NBUCK + 1, 256, 0, stream>>>(
        tmp, ccur, embeds, item_beg, item_end, nbr, ebfS, bb1, invrow);

    // --- layers 1,2: XCD-specialized dynamic work assignment ---
    const int blocks = U_UNITS + I_UNITS;   // 37500
    agg_kernel<<<blocks, 256, 0, stream>>>(ebfS, buf1, bb1, invrow, flags, user_ptr,
                                           cols16, item_beg, item_end, nbr, ctrs);
    agg_kernel<<<blocks, 256, 0, stream>>>(bb1, buf2, ebfS, invrow, flags, user_ptr,
                                           cols16, item_beg, item_end, nbr, ctrs + 2);  // bb2 = ebfS

    // --- layer 3 + epilogue fused: only the 3*B output slots ---
    agg3_fused_kernel<<<(3 * B + 3) / 4, 256, 0, stream>>>(
        ebfS, embeds, buf1, buf2, invrow, users, pos, neg,
        user_ptr, cols16, item_beg, item_end, nbr, (float*)d_out, B);
}

// Round 12
// 342.887 us; speedup vs baseline: 3.5165x; 3.5165x over previous
//
#include <hip/hip_runtime.h>
#include <hip/hip_bf16.h>

#define N_USERS 100000
#define N_ITEMS 50000
#define N_TOT   150000
#define D       64
#define NBUCK   ((N_ITEMS + 255) >> 8)   // 196 coarse buckets of 256 items
#define BCAP    12288                    // bucket capacity (mean ~10.2K, +18 sigma)
#define CONVU_B 391                      // ceil(100000/256): user conv blocks
#define FLAG_B  48                       // ceil(3*4096/256)
#define SCAT_K  32                       // edges per thread in scatter section

typedef float v2f __attribute__((ext_vector_type(2)));

// ---------------- helpers ----------------
__device__ __forceinline__ unsigned bf16rn(float f) {        // fp32 -> bf16 bits (RNE)
    unsigned x = __float_as_uint(f);
    return (x + 0x7FFFu + ((x >> 16) & 1u)) >> 16;
}
__device__ __forceinline__ unsigned packbf(float a, float b) {
    return bf16rn(a) | (bf16rn(b) << 16);
}

// ---------------- preprocessing kernel A ----------------
// Sections: [0,FLAG_B): flags | rest: LDS-buffered coarse scatter (K=32)
//           fused with edge-driven user_ptr boundary fill (rows is sorted).
__global__ __launch_bounds__(256) void preA_kernel(
        const int* __restrict__ rows, const int* __restrict__ cols,
        int* __restrict__ user_ptr,
        const int* __restrict__ users, const int* __restrict__ pos,
        const int* __restrict__ neg, unsigned char* __restrict__ flags,
        int* __restrict__ ccur, int* __restrict__ tmp,
        unsigned short* __restrict__ cols16, int E, int B) {
    int b = blockIdx.x, t = threadIdx.x;
    if (b < FLAG_B) {
        int k = b * 256 + t;
        if (k < 3 * B) {
            int row;
            if (k < B)          row = users[k];
            else if (k < 2 * B) row = N_USERS + pos[k - B];
            else                row = N_USERS + neg[k - 2 * B];
            flags[row] = 1;
        }
    } else {
        __shared__ int ebuf[256 * SCAT_K];            // 32 KB payloads
        __shared__ unsigned char bbuf[256 * SCAT_K];  // 8 KB bucket ids
        __shared__ int cnt[NBUCK];
        __shared__ int basep[NBUCK];
        int chunk = (b - FLAG_B) * (256 * SCAT_K);
        if (t < NBUCK) cnt[t] = 0;
        __syncthreads();
        #pragma unroll 4
        for (int k = 0; k < SCAT_K; ++k) {
            int e = chunk + k * 256 + t;
            int idx = k * 256 + t;
            if (e < E) {
                int i = cols[e] - N_USERS;
                int u = rows[e];
                cols16[e] = (unsigned short)i;
                int bu = i >> 8;
                ebuf[idx] = ((i & 255) << 17) | u;
                bbuf[idx] = (unsigned char)bu;
                atomicAdd(&cnt[bu], 1);
                // edge-driven user_ptr fill: user_ptr[r] = lower_bound(rows, r)
                int rnext = (e + 1 < E) ? rows[e + 1] : N_USERS;
                for (int r = u + 1; r <= rnext; ++r) user_ptr[r] = e + 1;
                if (e == 0) for (int r = 0; r <= u; ++r) user_ptr[r] = 0;
            } else bbuf[idx] = 255;                    // invalid (>195)
        }
        __syncthreads();
        if (t < NBUCK) {
            int c = cnt[t];
            basep[t] = c ? atomicAdd(&ccur[t], c) : 0;
            cnt[t] = 0;
        }
        __syncthreads();
        #pragma unroll 4
        for (int k = 0; k < SCAT_K; ++k) {
            int idx = k * 256 + t;
            int bu = bbuf[idx];
            if (bu < NBUCK) {
                int pos2 = basep[bu] + atomicAdd(&cnt[bu], 1);
                if (pos2 < BCAP)
                    tmp[(size_t)bu * BCAP + pos2] = ebuf[idx];
            }
        }
    }
}

// ---------------- preprocessing kernel B ----------------
// Blocks [0,NBUCK): fine sort + item inv + item-row conversion.
// Blocks [NBUCK, NBUCK+CONVU_B): user inv + user-row conversion (user_ptr ready).
// Last block: zero row init.
__global__ __launch_bounds__(256) void preB_kernel(
        const int* __restrict__ tmp, const int* __restrict__ ccur,
        const float* __restrict__ embeds, const int* __restrict__ user_ptr,
        int* __restrict__ item_beg, int* __restrict__ item_end,
        int* __restrict__ nbr, unsigned* __restrict__ ebfS,
        unsigned* __restrict__ bb1, float* __restrict__ invrow) {
    int b = blockIdx.x, t = threadIdx.x;
    if (b >= NBUCK) {
        if (b == NBUCK + CONVU_B) {   // zero row
            if (t < 16) {
                *(uint2*)(ebfS + (size_t)N_TOT * 32 + t * 2) = make_uint2(0u, 0u);
                *(uint2*)(bb1  + (size_t)N_TOT * 32 + t * 2) = make_uint2(0u, 0u);
            }
            if (t == 0) invrow[N_TOT] = 0.f;
            return;
        }
        // user conversion
        __shared__ int ptr_s[257];
        __shared__ float inv_s[256];
        int base = (b - NBUCK) * 256;
        int r = base + t;
        ptr_s[t] = (r <= N_USERS) ? user_ptr[r] : 0;
        if (t == 0) ptr_s[256] = (base + 256 <= N_USERS) ? user_ptr[base + 256] : 0;
        __syncthreads();
        if (r < N_USERS) {
            int deg = ptr_s[t + 1] - ptr_s[t];
            float inv = (deg > 0) ? (float)(1.0 / sqrt((double)deg)) : 0.f;
            inv_s[t] = inv;
            invrow[r] = inv;
        } else inv_s[t] = 0.f;
        __syncthreads();
        int fl = t & 15;
        #pragma unroll
        for (int i = 0; i < 16; ++i) {
            int lr = i * 16 + (t >> 4);
            int row = base + lr;
            if (row < N_USERS) {
                float inv = inv_s[lr];
                float4 v4 = *(const float4*)(embeds + (size_t)row * D + fl * 4);
                uint2 o;
                o.x = packbf(inv * v4.x, inv * v4.y);
                o.y = packbf(inv * v4.z, inv * v4.w);
                *(uint2*)(ebfS + (size_t)row * 32 + fl * 2) = o;
            }
        }
        return;
    }
    __shared__ int stage[BCAP];    // 48 KB
    __shared__ int hist[256];
    __shared__ int scn[256];
    __shared__ int curs[256];
    __shared__ float inv_s[256];
    int n = ccur[b]; if (n > BCAP) n = BCAP;
    const int* src = tmp + (size_t)b * BCAP;
    hist[t] = 0;
    __syncthreads();
    for (int p = t; p < n; p += 256) {
        int q = src[p];
        stage[p] = q;
        atomicAdd(&hist[q >> 17], 1);
    }
    __syncthreads();
    scn[t] = hist[t];
    __syncthreads();
    for (int off = 1; off < 256; off <<= 1) {
        int x = (t >= off) ? scn[t - off] : 0;
        __syncthreads();
        scn[t] += x;
        __syncthreads();
    }
    {
        int excl = scn[t] - hist[t];
        curs[t] = excl;
        int gi = (b << 8) + t;
        float inv = (hist[t] > 0) ? (float)(1.0 / sqrt((double)hist[t])) : 0.f;
        inv_s[t] = inv;
        if (gi < N_ITEMS) {
            item_beg[gi] = b * BCAP + excl;
            item_end[gi] = b * BCAP + excl + hist[t];
            invrow[N_USERS + gi] = inv;
        }
    }
    __syncthreads();
    int* dst = nbr + (size_t)b * BCAP;
    for (int p = t; p < n; p += 256) {
        int q = stage[p];
        int pos = atomicAdd(&curs[q >> 17], 1);
        dst[pos] = q & 0x1FFFF;
    }
    int fl = t & 15;
    #pragma unroll
    for (int i = 0; i < 16; ++i) {
        int lr = i * 16 + (t >> 4);
        int gi = (b << 8) + lr;
        if (gi < N_ITEMS) {
            int row = N_USERS + gi;
            float inv = inv_s[lr];
            float4 v4 = *(const float4*)(embeds + (size_t)row * D + fl * 4);
            uint2 o;
            o.x = packbf(inv * v4.x, inv * v4.y);
            o.y = packbf(inv * v4.z, inv * v4.w);
            *(uint2*)(ebfS + (size_t)row * 32 + fl * 2) = o;
        }
    }
}

// ---------------- propagation (layers 1,2: all rows) ----------------
// One wave per destination row; 8 lanes/edge (uint4 = 8 bf16), 8 edges in
// flight; metadata preloaded 64-wide, broadcast via shfl; full unroll-8 so
// all 8 gathers issue before the first waitcnt (one latency round/chunk).
__global__ __launch_bounds__(256) void agg_kernel(
        const unsigned* __restrict__ gsrc,   // scaled bf16 rows, 32 uints/row
        float* __restrict__ nxt, unsigned* __restrict__ nxtb,
        const float* __restrict__ invrow,
        const unsigned char* __restrict__ flags,
        const int* __restrict__ user_ptr, const unsigned short* __restrict__ cols16,
        const int* __restrict__ item_beg, const int* __restrict__ item_end,
        const int* __restrict__ nbr) {
    int wave = (int)((blockIdx.x * blockDim.x + threadIdx.x) >> 6);
    int lane = (int)(threadIdx.x & 63);
    if (wave >= N_TOT) return;
    int g  = lane >> 3;
    int fl = lane & 7;

    bool is_user = wave < N_USERS;
    int s, epos, dummy;
    const unsigned* sb;
    if (is_user) {
        s = user_ptr[wave]; epos = user_ptr[wave + 1];
        sb = gsrc + (size_t)N_USERS * 32; dummy = N_ITEMS;
    } else {
        int i = wave - N_USERS; s = item_beg[i]; epos = item_end[i];
        sb = gsrc; dummy = N_TOT;
    }

    v2f a0 = {0.f, 0.f}, a1 = {0.f, 0.f}, a2 = {0.f, 0.f}, a3 = {0.f, 0.f};

    for (int base = s; base < epos; base += 64) {
        int cnt = epos - base; if (cnt > 64) cnt = 64;
        int col = dummy;
        if (lane < cnt)
            col = is_user ? (int)cols16[base + lane] : nbr[base + lane];
        int tcount = (cnt + 7) >> 3;
        #pragma unroll 8
        for (int t = 0; t < tcount; ++t) {
            int c = __shfl(col, 8 * t + g);
            uint4 q = *(const uint4*)(sb + (size_t)c * 32 + fl * 4);
            v2f p0 = {__uint_as_float(q.x << 16), __uint_as_float(q.x & 0xFFFF0000u)};
            v2f p1 = {__uint_as_float(q.y << 16), __uint_as_float(q.y & 0xFFFF0000u)};
            v2f p2 = {__uint_as_float(q.z << 16), __uint_as_float(q.z & 0xFFFF0000u)};
            v2f p3 = {__uint_as_float(q.w << 16), __uint_as_float(q.w & 0xFFFF0000u)};
            a0 += p0; a1 += p1; a2 += p2; a3 += p3;
        }
    }
    float acc[8] = {a0.x, a0.y, a1.x, a1.y, a2.x, a2.y, a3.x, a3.y};
    #pragma unroll
    for (int j = 0; j < 8; ++j) {
        acc[j] += __shfl_xor(acc[j], 8);
        acc[j] += __shfl_xor(acc[j], 16);
        acc[j] += __shfl_xor(acc[j], 32);
    }
    if (lane < 8) {
        float inv = invrow[wave];
        float f[8];
        #pragma unroll
        for (int j = 0; j < 8; ++j) f[j] = inv * acc[j];
        uint4 o;
        o.x = packbf(inv * f[0], inv * f[1]); o.y = packbf(inv * f[2], inv * f[3]);
        o.z = packbf(inv * f[4], inv * f[5]); o.w = packbf(inv * f[6], inv * f[7]);
        *(uint4*)(nxtb + (size_t)wave * 32 + fl * 4) = o;
        if (flags[wave]) {
            size_t ro = (size_t)wave * D + fl * 8;
            *(float4*)(nxt + ro)     = make_float4(f[0], f[1], f[2], f[3]);
            *(float4*)(nxt + ro + 4) = make_float4(f[4], f[5], f[6], f[7]);
        }
    }
}

// ---------------- layer 3 fused with epilogue: only output slots ----------------
__global__ __launch_bounds__(256) void agg3_fused_kernel(
        const unsigned* __restrict__ gsrc,
        const float* __restrict__ e0, const float* __restrict__ e1,
        const float* __restrict__ e2, const float* __restrict__ invrow,
        const int* __restrict__ users, const int* __restrict__ pos,
        const int* __restrict__ neg,
        const int* __restrict__ user_ptr, const unsigned short* __restrict__ cols16,
        const int* __restrict__ item_beg, const int* __restrict__ item_end,
        const int* __restrict__ nbr,
        float* __restrict__ out, int B) {
    int slot = (int)((blockIdx.x * blockDim.x + threadIdx.x) >> 6);
    int lane = (int)(threadIdx.x & 63);
    if (slot >= 3 * B) return;
    int g  = lane >> 3;
    int fl = lane & 7;

    int row;
    if (slot < B)          row = users[slot];
    else if (slot < 2 * B) row = N_USERS + pos[slot - B];
    else                   row = N_USERS + neg[slot - 2 * B];

    bool is_user = row < N_USERS;
    int s, epos, dummy;
    const unsigned* sb;
    if (is_user) {
        s = user_ptr[row]; epos = user_ptr[row + 1];
        sb = gsrc + (size_t)N_USERS * 32; dummy = N_ITEMS;
    } else {
        int i = row - N_USERS; s = item_beg[i]; epos = item_end[i];
        sb = gsrc; dummy = N_TOT;
    }

    v2f a0 = {0.f, 0.f}, a1 = {0.f, 0.f}, a2 = {0.f, 0.f}, a3 = {0.f, 0.f};

    for (int base = s; base < epos; base += 64) {
        int cnt = epos - base; if (cnt > 64) cnt = 64;
        int col = dummy;
        if (lane < cnt)
            col = is_user ? (int)cols16[base + lane] : nbr[base + lane];
        int tcount = (cnt + 7) >> 3;
        #pragma unroll 8
        for (int t = 0; t < tcount; ++t) {
            int c = __shfl(col, 8 * t + g);
            uint4 q = *(const uint4*)(sb + (size_t)c * 32 + fl * 4);
            v2f p0 = {__uint_as_float(q.x << 16), __uint_as_float(q.x & 0xFFFF0000u)};
            v2f p1 = {__uint_as_float(q.y << 16), __uint_as_float(q.y & 0xFFFF0000u)};
            v2f p2 = {__uint_as_float(q.z << 16), __uint_as_float(q.z & 0xFFFF0000u)};
            v2f p3 = {__uint_as_float(q.w << 16), __uint_as_float(q.w & 0xFFFF0000u)};
            a0 += p0; a1 += p1; a2 += p2; a3 += p3;
        }
    }
    float acc[8] = {a0.x, a0.y, a1.x, a1.y, a2.x, a2.y, a3.x, a3.y};
    #pragma unroll
    for (int j = 0; j < 8; ++j) {
        acc[j] += __shfl_xor(acc[j], 8);
        acc[j] += __shfl_xor(acc[j], 16);
        acc[j] += __shfl_xor(acc[j], 32);
    }
    if (lane < 8) {
        float inv = invrow[row];
        size_t ro = (size_t)row * D + fl * 8;
        float4 x0 = *(const float4*)(e0 + ro), x1 = *(const float4*)(e0 + ro + 4);
        float4 y0 = *(const float4*)(e1 + ro), y1 = *(const float4*)(e1 + ro + 4);
        float4 z0 = *(const float4*)(e2 + ro), z1 = *(const float4*)(e2 + ro + 4);
        float4 r0, r1;
        r0.x = (x0.x + y0.x + z0.x + inv * acc[0]) * 0.25f;
        r0.y = (x0.y + y0.y + z0.y + inv * acc[1]) * 0.25f;
        r0.z = (x0.z + y0.z + z0.z + inv * acc[2]) * 0.25f;
        r0.w = (x0.w + y0.w + z0.w + inv * acc[3]) * 0.25f;
        r1.x = (x1.x + y1.x + z1.x + inv * acc[4]) * 0.25f;
        r1.y = (x1.y + y1.y + z1.y + inv * acc[5]) * 0.25f;
        r1.z = (x1.z + y1.z + z1.z + inv * acc[6]) * 0.25f;
        r1.w = (x1.w + y1.w + z1.w + inv * acc[7]) * 0.25f;
        size_t oo = (size_t)slot * D + fl * 8;
        *(float4*)(out + oo)     = r0;
        *(float4*)(out + oo + 4) = r1;
    }
}

extern "C" void kernel_launch(void* const* d_in, const int* in_sizes, int n_in,
                              void* d_out, int out_size, void* d_ws, size_t ws_size,
                              hipStream_t stream) {
    const float* embeds = (const float*)d_in[0];
    const int*   rows   = (const int*)d_in[2];
    const int*   cols   = (const int*)d_in[3];
    const int*   users  = (const int*)d_in[4];
    const int*   pos    = (const int*)d_in[5];
    const int*   neg    = (const int*)d_in[6];
    const int E2 = in_sizes[1];
    const int E  = E2 / 2;
    const int B  = in_sizes[4];

    char* ws = (char*)d_ws;
    size_t off = 0;
    auto alloc = [&](size_t bytes) { void* p = ws + off; off = (off + bytes + 255) & ~(size_t)255; return p; };
    float*    buf1     = (float*)   alloc((size_t)N_TOT * D * sizeof(float));     // flagged fp32 L1
    float*    buf2     = (float*)   alloc((size_t)N_TOT * D * sizeof(float));     // flagged fp32 L2
    unsigned* ebfS     = (unsigned*)alloc((size_t)(N_TOT + 1) * 32 * sizeof(unsigned)); // scaled bf16 (+zero row); reused as bb2
    unsigned* bb1      = (unsigned*)alloc((size_t)(N_TOT + 1) * 32 * sizeof(unsigned));
    int*      nbr      = (int*)     alloc((size_t)NBUCK * BCAP * sizeof(int));    // padded item CSR (user idx)
    unsigned short* cols16 = (unsigned short*)alloc((size_t)E * sizeof(unsigned short));
    int*      user_ptr = (int*)     alloc((size_t)(N_USERS + 1) * sizeof(int));
    int*      ccur     = (int*)     alloc((size_t)NBUCK * sizeof(int));
    int*      item_beg = (int*)     alloc((size_t)N_ITEMS * sizeof(int));
    int*      item_end = (int*)     alloc((size_t)N_ITEMS * sizeof(int));
    float*    invrow   = (float*)   alloc((size_t)(N_TOT + 1) * sizeof(float));
    unsigned char* flags = (unsigned char*)alloc((size_t)N_TOT);
    int*      tmp      = (int*)buf1;   // alias: buf1 written only after preB

    // --- preprocessing (2 fused kernels) ---
    hipMemsetAsync(ccur, 0, (size_t)NBUCK * sizeof(int), stream);
    hipMemsetAsync(flags, 0, (size_t)N_TOT, stream);
    const int scatB = (E + 256 * SCAT_K - 1) / (256 * SCAT_K);
    preA_kernel<<<FLAG_B + scatB, 256, 0, stream>>>(
        rows, cols, user_ptr, users, pos, neg, flags, ccur, tmp, cols16, E, B);
    preB_kernel<<<NBUCK + CONVU_B + 1, 256, 0, stream>>>(
        tmp, ccur, embeds, user_ptr, item_beg, item_end, nbr, ebfS, bb1, invrow);

    // --- layers 1,2: all rows (scaled bf16 out + flagged fp32 out) ---
    const int blocks = (N_TOT + 3) / 4;
    agg_kernel<<<blocks, 256, 0, stream>>>(ebfS, buf1, bb1, invrow, flags, user_ptr,
                                           cols16, item_beg, item_end, nbr);
    agg_kernel<<<blocks, 256, 0, stream>>>(bb1, buf2, ebfS, invrow, flags, user_ptr,
                                           cols16, item_beg, item_end, nbr);  // bb2 = ebfS

    // --- layer 3 + epilogue fused: only the 3*B output slots ---
    agg3_fused_kernel<<<(3 * B + 3) / 4, 256, 0, stream>>>(
        ebfS, embeds, buf1, buf2, invrow, users, pos, neg,
        user_ptr, cols16, item_beg, item_end, nbr, (float*)d_out, B);
}

// Round 13
// 324.788 us; speedup vs baseline: 3.7125x; 1.0557x over previous
//
#include <hip/hip_runtime.h>
#include <hip/hip_bf16.h>

#define N_USERS 100000
#define N_ITEMS 50000
#define N_TOT   150000
#define D       64
#define NBUCK   ((N_ITEMS + 255) >> 8)   // 196 coarse buckets of 256 items
#define BCAP    12288                    // bucket capacity (mean ~10.2K, +18 sigma)
#define CONVU_B 391                      // ceil(100000/256): user conv+ptr blocks
#define FLAG_B  48                       // ceil(3*4096/256)
#define SCAT_K  32                       // edges per thread in scatter section

typedef float v2f __attribute__((ext_vector_type(2)));

// ---------------- helpers ----------------
__device__ __forceinline__ unsigned bf16rn(float f) {        // fp32 -> bf16 bits (RNE)
    unsigned x = __float_as_uint(f);
    return (x + 0x7FFFu + ((x >> 16) & 1u)) >> 16;
}
__device__ __forceinline__ unsigned packbf(float a, float b) {
    return bf16rn(a) | (bf16rn(b) << 16);
}
__device__ __forceinline__ int lower_bound(const int* __restrict__ a, int n, int key) {
    int lo = 0, hi = n;
    while (lo < hi) {
        int mid = (lo + hi) >> 1;
        if (a[mid] < key) lo = mid + 1; else hi = mid;
    }
    return lo;
}

// ---------------- preprocessing kernel A ----------------
// Sections: [0,CONVU_B): user_ptr bsearch + user inv + user-row conversion
//           [CONVU_B,+FLAG_B): flags
//           rest: LDS-buffered coarse scatter (K=32, 256-item buckets)
__global__ __launch_bounds__(256) void preA_kernel(
        const float* __restrict__ embeds, const int* __restrict__ rows,
        const int* __restrict__ cols, int* __restrict__ user_ptr,
        unsigned* __restrict__ ebfS, float* __restrict__ invrow,
        const int* __restrict__ users, const int* __restrict__ pos,
        const int* __restrict__ neg, unsigned char* __restrict__ flags,
        int* __restrict__ ccur, int* __restrict__ tmp,
        unsigned short* __restrict__ cols16, int E, int B) {
    int b = blockIdx.x, t = threadIdx.x;
    if (b < CONVU_B) {
        __shared__ int ptr_s[257];
        __shared__ float inv_s[256];
        int base = b * 256;
        int r = base + t;
        int v = lower_bound(rows, E, r);
        ptr_s[t] = v;
        if (r <= N_USERS) user_ptr[r] = v;
        if (t == 0) ptr_s[256] = lower_bound(rows, E, base + 256);
        __syncthreads();
        if (r < N_USERS) {
            int deg = ptr_s[t + 1] - ptr_s[t];
            float inv = (deg > 0) ? (float)(1.0 / sqrt((double)deg)) : 0.f;
            inv_s[t] = inv;
            invrow[r] = inv;
        } else inv_s[t] = 0.f;
        __syncthreads();
        int fl = t & 15;
        #pragma unroll
        for (int i = 0; i < 16; ++i) {
            int lr = i * 16 + (t >> 4);
            int row = base + lr;
            if (row < N_USERS) {
                float inv = inv_s[lr];
                float4 v4 = *(const float4*)(embeds + (size_t)row * D + fl * 4);
                uint2 o;
                o.x = packbf(inv * v4.x, inv * v4.y);
                o.y = packbf(inv * v4.z, inv * v4.w);
                *(uint2*)(ebfS + (size_t)row * 32 + fl * 2) = o;
            }
        }
    } else if (b < CONVU_B + FLAG_B) {
        int k = (b - CONVU_B) * 256 + t;
        if (k < 3 * B) {
            int row;
            if (k < B)          row = users[k];
            else if (k < 2 * B) row = N_USERS + pos[k - B];
            else                row = N_USERS + neg[k - 2 * B];
            flags[row] = 1;
        }
    } else {
        __shared__ int ebuf[256 * SCAT_K];            // 32 KB payloads
        __shared__ unsigned char bbuf[256 * SCAT_K];  // 8 KB bucket ids
        __shared__ int cnt[NBUCK];
        __shared__ int basep[NBUCK];
        int chunk = (b - CONVU_B - FLAG_B) * (256 * SCAT_K);
        if (t < NBUCK) cnt[t] = 0;
        __syncthreads();
        #pragma unroll 8
        for (int k = 0; k < SCAT_K; ++k) {
            int e = chunk + k * 256 + t;
            int idx = k * 256 + t;
            if (e < E) {
                int i = cols[e] - N_USERS;
                cols16[e] = (unsigned short)i;
                int bu = i >> 8;
                ebuf[idx] = ((i & 255) << 17) | rows[e];
                bbuf[idx] = (unsigned char)bu;
                atomicAdd(&cnt[bu], 1);
            } else bbuf[idx] = 255;                    // invalid (>195)
        }
        __syncthreads();
        if (t < NBUCK) {
            int c = cnt[t];
            basep[t] = c ? atomicAdd(&ccur[t], c) : 0;
            cnt[t] = 0;
        }
        __syncthreads();
        #pragma unroll 4
        for (int k = 0; k < SCAT_K; ++k) {
            int idx = k * 256 + t;
            int bu = bbuf[idx];
            if (bu < NBUCK) {
                int pos2 = basep[bu] + atomicAdd(&cnt[bu], 1);
                if (pos2 < BCAP)
                    tmp[(size_t)bu * BCAP + pos2] = ebuf[idx];
            }
        }
    }
}

// ---------------- preprocessing kernel B ----------------
// Blocks [0,NBUCK): fine sort (int4-staged) + item inv + item-row conversion.
// Block NBUCK: zero row init.
__global__ __launch_bounds__(256) void preB_kernel(
        const int* __restrict__ tmp, const int* __restrict__ ccur,
        const float* __restrict__ embeds,
        int* __restrict__ item_beg, int* __restrict__ item_end,
        int* __restrict__ nbr, unsigned* __restrict__ ebfS,
        unsigned* __restrict__ bb1, float* __restrict__ invrow) {
    int b = blockIdx.x, t = threadIdx.x;
    if (b == NBUCK) {
        if (t < 16) {
            *(uint2*)(ebfS + (size_t)N_TOT * 32 + t * 2) = make_uint2(0u, 0u);
            *(uint2*)(bb1  + (size_t)N_TOT * 32 + t * 2) = make_uint2(0u, 0u);
        }
        if (t == 0) invrow[N_TOT] = 0.f;
        return;
    }
    __shared__ int stage[BCAP];    // 48 KB
    __shared__ int hist[256];
    __shared__ int scn[256];
    __shared__ int curs[256];
    __shared__ float inv_s[256];
    int n = ccur[b]; if (n > BCAP) n = BCAP;
    const int* src = tmp + (size_t)b * BCAP;
    hist[t] = 0;
    __syncthreads();
    // int4 staging: 4x fewer dependent load rounds
    int n4 = n >> 2;
    const int4* src4 = (const int4*)src;
    for (int p = t; p < n4; p += 256) {
        int4 q = src4[p];
        *(int4*)(stage + p * 4) = q;
        atomicAdd(&hist[q.x >> 17], 1);
        atomicAdd(&hist[q.y >> 17], 1);
        atomicAdd(&hist[q.z >> 17], 1);
        atomicAdd(&hist[q.w >> 17], 1);
    }
    for (int p = (n4 << 2) + t; p < n; p += 256) {
        int q = src[p];
        stage[p] = q;
        atomicAdd(&hist[q >> 17], 1);
    }
    __syncthreads();
    scn[t] = hist[t];
    __syncthreads();
    for (int off = 1; off < 256; off <<= 1) {
        int x = (t >= off) ? scn[t - off] : 0;
        __syncthreads();
        scn[t] += x;
        __syncthreads();
    }
    {
        int excl = scn[t] - hist[t];
        curs[t] = excl;
        int gi = (b << 8) + t;
        float inv = (hist[t] > 0) ? (float)(1.0 / sqrt((double)hist[t])) : 0.f;
        inv_s[t] = inv;
        if (gi < N_ITEMS) {
            item_beg[gi] = b * BCAP + excl;
            item_end[gi] = b * BCAP + excl + hist[t];
            invrow[N_USERS + gi] = inv;
        }
    }
    __syncthreads();
    int* dst = nbr + (size_t)b * BCAP;
    for (int p = t; p < n4; p += 256) {
        int4 q = *(const int4*)(stage + p * 4);
        int p0 = atomicAdd(&curs[q.x >> 17], 1); dst[p0] = q.x & 0x1FFFF;
        int p1 = atomicAdd(&curs[q.y >> 17], 1); dst[p1] = q.y & 0x1FFFF;
        int p2 = atomicAdd(&curs[q.z >> 17], 1); dst[p2] = q.z & 0x1FFFF;
        int p3 = atomicAdd(&curs[q.w >> 17], 1); dst[p3] = q.w & 0x1FFFF;
    }
    for (int p = (n4 << 2) + t; p < n; p += 256) {
        int q = stage[p];
        int pos = atomicAdd(&curs[q >> 17], 1);
        dst[pos] = q & 0x1FFFF;
    }
    int fl = t & 15;
    #pragma unroll
    for (int i = 0; i < 16; ++i) {
        int lr = i * 16 + (t >> 4);
        int gi = (b << 8) + lr;
        if (gi < N_ITEMS) {
            int row = N_USERS + gi;
            float inv = inv_s[lr];
            float4 v4 = *(const float4*)(embeds + (size_t)row * D + fl * 4);
            uint2 o;
            o.x = packbf(inv * v4.x, inv * v4.y);
            o.y = packbf(inv * v4.z, inv * v4.w);
            *(uint2*)(ebfS + (size_t)row * 32 + fl * 2) = o;
        }
    }
}

// ---------------- propagation (layers 1,2: all rows) ----------------
__global__ __launch_bounds__(256) void agg_kernel(
        const unsigned* __restrict__ gsrc,   // scaled bf16 rows, 32 uints/row
        float* __restrict__ nxt, unsigned* __restrict__ nxtb,
        const float* __restrict__ invrow,
        const unsigned char* __restrict__ flags,
        const int* __restrict__ user_ptr, const unsigned short* __restrict__ cols16,
        const int* __restrict__ item_beg, const int* __restrict__ item_end,
        const int* __restrict__ nbr) {
    int wave = (int)((blockIdx.x * blockDim.x + threadIdx.x) >> 6);
    int lane = (int)(threadIdx.x & 63);
    if (wave >= N_TOT) return;
    int g  = lane >> 3;
    int fl = lane & 7;

    bool is_user = wave < N_USERS;
    int s, epos, dummy;
    const unsigned* sb;
    if (is_user) {
        s = user_ptr[wave]; epos = user_ptr[wave + 1];
        sb = gsrc + (size_t)N_USERS * 32; dummy = N_ITEMS;
    } else {
        int i = wave - N_USERS; s = item_beg[i]; epos = item_end[i];
        sb = gsrc; dummy = N_TOT;
    }

    v2f a0 = {0.f, 0.f}, a1 = {0.f, 0.f}, a2 = {0.f, 0.f}, a3 = {0.f, 0.f};

    for (int base = s; base < epos; base += 64) {
        int cnt = epos - base; if (cnt > 64) cnt = 64;
        int col = dummy;
        if (lane < cnt)
            col = is_user ? (int)cols16[base + lane] : nbr[base + lane];
        int tcount = (cnt + 7) >> 3;
        #pragma unroll 8
        for (int t = 0; t < tcount; ++t) {
            int c = __shfl(col, 8 * t + g);
            uint4 q = *(const uint4*)(sb + (size_t)c * 32 + fl * 4);
            v2f p0 = {__uint_as_float(q.x << 16), __uint_as_float(q.x & 0xFFFF0000u)};
            v2f p1 = {__uint_as_float(q.y << 16), __uint_as_float(q.y & 0xFFFF0000u)};
            v2f p2 = {__uint_as_float(q.z << 16), __uint_as_float(q.z & 0xFFFF0000u)};
            v2f p3 = {__uint_as_float(q.w << 16), __uint_as_float(q.w & 0xFFFF0000u)};
            a0 += p0; a1 += p1; a2 += p2; a3 += p3;
        }
    }
    float acc[8] = {a0.x, a0.y, a1.x, a1.y, a2.x, a2.y, a3.x, a3.y};
    #pragma unroll
    for (int j = 0; j < 8; ++j) {
        acc[j] += __shfl_xor(acc[j], 8);
        acc[j] += __shfl_xor(acc[j], 16);
        acc[j] += __shfl_xor(acc[j], 32);
    }
    if (lane < 8) {
        float inv = invrow[wave];
        float f[8];
        #pragma unroll
        for (int j = 0; j < 8; ++j) f[j] = inv * acc[j];
        uint4 o;
        o.x = packbf(inv * f[0], inv * f[1]); o.y = packbf(inv * f[2], inv * f[3]);
        o.z = packbf(inv * f[4], inv * f[5]); o.w = packbf(inv * f[6], inv * f[7]);
        *(uint4*)(nxtb + (size_t)wave * 32 + fl * 4) = o;
        if (flags[wave]) {
            size_t ro = (size_t)wave * D + fl * 8;
            *(float4*)(nxt + ro)     = make_float4(f[0], f[1], f[2], f[3]);
            *(float4*)(nxt + ro + 4) = make_float4(f[4], f[5], f[6], f[7]);
        }
    }
}

// ---------------- layer 3 fused with epilogue: only output slots ----------------
__global__ __launch_bounds__(256) void agg3_fused_kernel(
        const unsigned* __restrict__ gsrc,
        const float* __restrict__ e0, const float* __restrict__ e1,
        const float* __restrict__ e2, const float* __restrict__ invrow,
        const int* __restrict__ users, const int* __restrict__ pos,
        const int* __restrict__ neg,
        const int* __restrict__ user_ptr, const unsigned short* __restrict__ cols16,
        const int* __restrict__ item_beg, const int* __restrict__ item_end,
        const int* __restrict__ nbr,
        float* __restrict__ out, int B) {
    int slot = (int)((blockIdx.x * blockDim.x + threadIdx.x) >> 6);
    int lane = (int)(threadIdx.x & 63);
    if (slot >= 3 * B) return;
    int g  = lane >> 3;
    int fl = lane & 7;

    int row;
    if (slot < B)          row = users[slot];
    else if (slot < 2 * B) row = N_USERS + pos[slot - B];
    else                   row = N_USERS + neg[slot - 2 * B];

    bool is_user = row < N_USERS;
    int s, epos, dummy;
    const unsigned* sb;
    if (is_user) {
        s = user_ptr[row]; epos = user_ptr[row + 1];
        sb = gsrc + (size_t)N_USERS * 32; dummy = N_ITEMS;
    } else {
        int i = row - N_USERS; s = item_beg[i]; epos = item_end[i];
        sb = gsrc; dummy = N_TOT;
    }

    v2f a0 = {0.f, 0.f}, a1 = {0.f, 0.f}, a2 = {0.f, 0.f}, a3 = {0.f, 0.f};

    for (int base = s; base < epos; base += 64) {
        int cnt = epos - base; if (cnt > 64) cnt = 64;
        int col = dummy;
        if (lane < cnt)
            col = is_user ? (int)cols16[base + lane] : nbr[base + lane];
        int tcount = (cnt + 7) >> 3;
        #pragma unroll 8
        for (int t = 0; t < tcount; ++t) {
            int c = __shfl(col, 8 * t + g);
            uint4 q = *(const uint4*)(sb + (size_t)c * 32 + fl * 4);
            v2f p0 = {__uint_as_float(q.x << 16), __uint_as_float(q.x & 0xFFFF0000u)};
            v2f p1 = {__uint_as_float(q.y << 16), __uint_as_float(q.y & 0xFFFF0000u)};
            v2f p2 = {__uint_as_float(q.z << 16), __uint_as_float(q.z & 0xFFFF0000u)};
            v2f p3 = {__uint_as_float(q.w << 16), __uint_as_float(q.w & 0xFFFF0000u)};
            a0 += p0; a1 += p1; a2 += p2; a3 += p3;
        }
    }
    float acc[8] = {a0.x, a0.y, a1.x, a1.y, a2.x, a2.y, a3.x, a3.y};
    #pragma unroll
    for (int j = 0; j < 8; ++j) {
        acc[j] += __shfl_xor(acc[j], 8);
        acc[j] += __shfl_xor(acc[j], 16);
        acc[j] += __shfl_xor(acc[j], 32);
    }
    if (lane < 8) {
        float inv = invrow[row];
        size_t ro = (size_t)row * D + fl * 8;
        float4 x0 = *(const float4*)(e0 + ro), x1 = *(const float4*)(e0 + ro + 4);
        float4 y0 = *(const float4*)(e1 + ro), y1 = *(const float4*)(e1 + ro + 4);
        float4 z0 = *(const float4*)(e2 + ro), z1 = *(const float4*)(e2 + ro + 4);
        float4 r0, r1;
        r0.x = (x0.x + y0.x + z0.x + inv * acc[0]) * 0.25f;
        r0.y = (x0.y + y0.y + z0.y + inv * acc[1]) * 0.25f;
        r0.z = (x0.z + y0.z + z0.z + inv * acc[2]) * 0.25f;
        r0.w = (x0.w + y0.w + z0.w + inv * acc[3]) * 0.25f;
        r1.x = (x1.x + y1.x + z1.x + inv * acc[4]) * 0.25f;
        r1.y = (x1.y + y1.y + z1.y + inv * acc[5]) * 0.25f;
        r1.z = (x1.z + y1.z + z1.z + inv * acc[6]) * 0.25f;
        r1.w = (x1.w + y1.w + z1.w + inv * acc[7]) * 0.25f;
        size_t oo = (size_t)slot * D + fl * 8;
        *(float4*)(out + oo)     = r0;
        *(float4*)(out + oo + 4) = r1;
    }
}

extern "C" void kernel_launch(void* const* d_in, const int* in_sizes, int n_in,
                              void* d_out, int out_size, void* d_ws, size_t ws_size,
                              hipStream_t stream) {
    const float* embeds = (const float*)d_in[0];
    const int*   rows   = (const int*)d_in[2];
    const int*   cols   = (const int*)d_in[3];
    const int*   users  = (const int*)d_in[4];
    const int*   pos    = (const int*)d_in[5];
    const int*   neg    = (const int*)d_in[6];
    const int E2 = in_sizes[1];
    const int E  = E2 / 2;
    const int B  = in_sizes[4];

    char* ws = (char*)d_ws;
    size_t off = 0;
    auto alloc = [&](size_t bytes) { void* p = ws + off; off = (off + bytes + 255) & ~(size_t)255; return p; };
    float*    buf1     = (float*)   alloc((size_t)N_TOT * D * sizeof(float));     // flagged fp32 L1
    float*    buf2     = (float*)   alloc((size_t)N_TOT * D * sizeof(float));     // flagged fp32 L2
    unsigned* ebfS     = (unsigned*)alloc((size_t)(N_TOT + 1) * 32 * sizeof(unsigned)); // scaled bf16 (+zero row); reused as bb2
    unsigned* bb1      = (unsigned*)alloc((size_t)(N_TOT + 1) * 32 * sizeof(unsigned));
    int*      nbr      = (int*)     alloc((size_t)NBUCK * BCAP * sizeof(int));    // padded item CSR (user idx)
    unsigned short* cols16 = (unsigned short*)alloc((size_t)E * sizeof(unsigned short));
    int*      user_ptr = (int*)     alloc((size_t)(N_USERS + 1) * sizeof(int));
    int*      item_beg = (int*)     alloc((size_t)N_ITEMS * sizeof(int));
    int*      item_end = (int*)     alloc((size_t)N_ITEMS * sizeof(int));
    float*    invrow   = (float*)   alloc((size_t)(N_TOT + 1) * sizeof(float));
    // ccur + flags adjacent -> single memset covers both
    int*      ccur     = (int*)     alloc((size_t)NBUCK * sizeof(int));
    unsigned char* flags = (unsigned char*)alloc((size_t)N_TOT);
    int*      tmp      = (int*)buf1;   // alias: buf1 written only after preB

    // --- preprocessing (2 fused kernels, 1 merged memset) ---
    size_t zspan = ((char*)flags + N_TOT) - (char*)ccur;
    hipMemsetAsync(ccur, 0, zspan, stream);
    const int scatB = (E + 256 * SCAT_K - 1) / (256 * SCAT_K);
    preA_kernel<<<CONVU_B + FLAG_B + scatB, 256, 0, stream>>>(
        embeds, rows, cols, user_ptr, ebfS, invrow, users, pos, neg, flags,
        ccur, tmp, cols16, E, B);
    preB_kernel<<<NBUCK + 1, 256, 0, stream>>>(
        tmp, ccur, embeds, item_beg, item_end, nbr, ebfS, bb1, invrow);

    // --- layers 1,2: all rows (scaled bf16 out + flagged fp32 out) ---
    const int blocks = (N_TOT + 3) / 4;
    agg_kernel<<<blocks, 256, 0, stream>>>(ebfS, buf1, bb1, invrow, flags, user_ptr,
                                           cols16, item_beg, item_end, nbr);
    agg_kernel<<<blocks, 256, 0, stream>>>(bb1, buf2, ebfS, invrow, flags, user_ptr,
                                           cols16, item_beg, item_end, nbr);  // bb2 = ebfS

    // --- layer 3 + epilogue fused: only the 3*B output slots ---
    agg3_fused_kernel<<<(3 * B + 3) / 4, 256, 0, stream>>>(
        ebfS, embeds, buf1, buf2, invrow, users, pos, neg,
        user_ptr, cols16, item_beg, item_end, nbr, (float*)d_out, B);
}